// Round 3
// baseline (176.718 us; speedup 1.0000x reference)
//
#include <hip/hip_runtime.h>
#include <math.h>

// ---- compile-time physical constants (mirror the Python reference) ----
namespace k {
constexpr double dA     = 0.129907 + 0.095724;       // L_X + L_Y
constexpr double dR     = 4.0 * 0.0254;              // wheel radius
constexpr double dI     = 6.0;                       // inertia (== mass)
constexpr double dMOI   = 6.0 * (12.0 * 0.0254) * (12.0 * 0.0254) / 6.0;
constexpr float T_STALL   = (float)(5.4 / 100.0);
constexpr float INV_WFREE = (float)(1.0 / (1620.0 / 60.0 * 2.0 * 3.14159265358979323846));
constexpr float A         = (float)dA;
constexpr float INV_R     = (float)(1.0 / dR);
constexpr float INV_RI    = (float)(1.0 / (dR * dI));    // WT2LA rows 0,1 scale
constexpr float A_RMOI    = (float)(dA / (dR * dMOI));   // WT2LA row 2 scale
}

// native clang vector type: required by __builtin_nontemporal_store
typedef float f32x4 __attribute__((ext_vector_type(4)));

__device__ __forceinline__ float wheel_torque(float w, float m) {
    float p = m * w;
    // jnp.sign semantics: sign(0)=0 -> is_same_direction = 0.5
    float sgn = (float)(p > 0.0f) - (float)(p < 0.0f);
    float isd = 0.5f * (sgn + 1.0f);
    return k::T_STALL * (1.0f - fabsf(w) * isd * k::INV_WFREE) * m;
}

__device__ __forceinline__ void mecanum_elem(const float st[6],
                                             float m0, float m1, float m2, float m3,
                                             float o[6]) {
    float theta = st[2];
    float s, c;
    sincosf(theta, &s, &c);

    float v0 = st[3], v1 = st[4], v2 = st[5];

    // a2l = rot(cos(-t), sin(-t)) -> [[c, s, 0], [-s, c, 0], [0,0,1]]
    float lv0 = c * v0 + s * v1;
    float lv1 = c * v1 - s * v0;

    float al2 = k::A * v2;
    float w0 = (lv0 - lv1 - al2) * k::INV_R;
    float w1 = (lv0 + lv1 + al2) * k::INV_R;
    float w2 = (lv0 + lv1 - al2) * k::INV_R;
    float w3 = (lv0 - lv1 + al2) * k::INV_R;

    float t0 = wheel_torque(w0, m0);
    float t1 = wheel_torque(w1, m1);
    float t2 = wheel_torque(w2, m2);
    float t3 = wheel_torque(w3, m3);

    float la0 = (t0 + t1 + t2 + t3) * k::INV_RI;
    float la1 = (-t0 + t1 + t2 - t3) * k::INV_RI;
    float la2 = (-t0 + t1 - t2 + t3) * k::A_RMOI;

    // l2a = rot(cos(t), sin(t)) -> [[c,-s,0],[s,c,0],[0,0,1]]
    float aa0 = c * la0 - s * la1;
    float aa1 = s * la0 + c * la1;

    o[0] = st[3]; o[1] = st[4]; o[2] = st[5];
    o[3] = aa0; o[4] = aa1; o[5] = la2;
}

// ---------------------------------------------------------------------------
// R3: cross-iteration software pipeline (convoy breaker).
//
// R2 finding: occupancy 49%->~100% was NEUTRAL. In-flight bytes were never
// the limit; the limit is memory-pipe DUTY CYCLE. One-tile-per-thread means
// all resident waves load (burst) -> compute (memory idle) -> store (burst)
// in lockstep convoys, so HBM sees ~50% duty -> 2.5 TB/s.
//
// Fix: persistent grid-stride over 256-pair tiles with a per-wave
// double-buffered LDS slice. Per iteration:
//   1. ISSUE next tile's 3 global float4 loads into regs (no wait)
//   2. gather current tile from lds[cur], compute, stage results in-place
//   3. coalesced NT-store current tile from lds[cur]
//   4. ds_write prefetched regs -> lds[cur^1]  (compiler's vmcnt wait lands
//      HERE, after a full compute+store phase -> load latency hidden; loads
//      for tile t+1 are in flight during all of tile t's compute)
// Still ZERO __syncthreads(): all LDS exchange is same-wave program order
// (lockstep wave, in-order LDS pipe) — validated correct in R2's pass.
//
// LDS: 2 bufs x 4 waves x 192 float4 = 24,576 B -> 6 blocks/CU (24 waves/CU).
// Grid: 1536 = 6 blocks/CU x 256 CU, fully resident, ~5 tiles/thread.
// ---------------------------------------------------------------------------
#define PAIRS_PER_BLOCK 256
#define F4_PER_BLOCK    (PAIRS_PER_BLOCK * 3)
#define GRID_BLOCKS     1536

__global__ __launch_bounds__(256, 6) void mecanum_pipe_kernel(
    const float4* __restrict__ state4,
    const float* __restrict__ cd,
    float4* __restrict__ out4,
    int n_pairs) {
    __shared__ float4 s[2][F4_PER_BLOCK];   // 2 x 12 KB; per-wave slices of 192

    const int tid  = threadIdx.x;
    const int wave = tid >> 6;
    const int lane = tid & 63;
    const int ws   = wave * 192;            // this wave's float4 slice base
    const int total4 = n_pairs * 3;
    const int ntiles = (n_pairs + PAIRS_PER_BLOCK - 1) / PAIRS_PER_BLOCK;
    const int stride = gridDim.x;

    int tp = blockIdx.x;                    // current tile index
    if (tp >= ntiles) return;

    // batch-uniform motor duty: CD2MD @ control_duty
    float u0 = cd[0], u1 = cd[1], u2 = cd[2];
    float m0 = u0 - u1 - u2;
    float m1 = u0 + u1 + u2;
    float m2 = u0 + u1 - u2;
    float m3 = u0 - u1 + u2;

    // ---- prologue: load tile tp, stage into lds[0]
    {
        const int fb = tp * F4_PER_BLOCK + ws;
#pragma unroll
        for (int r = 0; r < 3; ++r) {
            int g = fb + r * 64 + lane;
            float4 v = (g < total4) ? state4[g] : make_float4(0.f, 0.f, 0.f, 0.f);
            s[0][ws + r * 64 + lane] = v;
        }
    }
    __builtin_amdgcn_wave_barrier();
    asm volatile("" ::: "memory");

    int cur = 0;
    while (true) {
        const int tnext = tp + stride;
        const bool have_next = tnext < ntiles;

        // ---- 1. issue next tile's loads (fire, don't wait)
        float4 n0, n1, n2;
        if (have_next) {
            const int fb = tnext * F4_PER_BLOCK + ws;
            int g0 = fb + 0 * 64 + lane;
            int g1 = fb + 1 * 64 + lane;
            int g2 = fb + 2 * 64 + lane;
            n0 = (g0 < total4) ? state4[g0] : make_float4(0.f, 0.f, 0.f, 0.f);
            n1 = (g1 < total4) ? state4[g1] : make_float4(0.f, 0.f, 0.f, 0.f);
            n2 = (g2 < total4) ? state4[g2] : make_float4(0.f, 0.f, 0.f, 0.f);
        }

        // ---- 2. gather current tile, compute, stage results in-place
        if (tp * PAIRS_PER_BLOCK + wave * 64 + lane < n_pairs) {
            float4 a  = s[cur][ws + 3 * lane + 0];
            float4 b  = s[cur][ws + 3 * lane + 1];
            float4 g4 = s[cur][ws + 3 * lane + 2];

            float stA[6] = { a.x, a.y, a.z, a.w, b.x, b.y };
            float stB[6] = { b.z, b.w, g4.x, g4.y, g4.z, g4.w };
            float oA[6], oB[6];
            mecanum_elem(stA, m0, m1, m2, m3, oA);
            mecanum_elem(stB, m0, m1, m2, m3, oB);

            s[cur][ws + 3 * lane + 0] = make_float4(oA[0], oA[1], oA[2], oA[3]);
            s[cur][ws + 3 * lane + 1] = make_float4(oA[4], oA[5], oB[0], oB[1]);
            s[cur][ws + 3 * lane + 2] = make_float4(oB[2], oB[3], oB[4], oB[5]);
        }
        __builtin_amdgcn_wave_barrier();
        asm volatile("" ::: "memory");

        // ---- 3. coalesced nontemporal store of current tile
        {
            const int fb = tp * F4_PER_BLOCK;
#pragma unroll
            for (int r = 0; r < 3; ++r) {
                int idx = ws + r * 64 + lane;
                int g = fb + idx;
                if (g < total4) {
                    float4 t = s[cur][idx];
                    f32x4 v;
                    v.x = t.x; v.y = t.y; v.z = t.z; v.w = t.w;
                    __builtin_nontemporal_store(v, (f32x4*)&out4[g]);
                }
            }
        }

        if (!have_next) break;

        // ---- 4. stage prefetched tile into the other buffer
        //        (vmcnt wait for n0..n2 happens here — latency already hidden)
        s[cur ^ 1][ws + 0 * 64 + lane] = n0;
        s[cur ^ 1][ws + 1 * 64 + lane] = n1;
        s[cur ^ 1][ws + 2 * 64 + lane] = n2;
        __builtin_amdgcn_wave_barrier();
        asm volatile("" ::: "memory");

        cur ^= 1;
        tp = tnext;
    }
}

// Scalar tail for odd batch sizes (defensive; BATCH=4M is even).
__global__ void mecanum_tail_kernel(const float* __restrict__ state,
                                    const float* __restrict__ cd,
                                    float* __restrict__ out,
                                    int start, int n) {
    int i = start + blockIdx.x * blockDim.x + threadIdx.x;
    if (i >= n) return;
    float u0 = cd[0], u1 = cd[1], u2 = cd[2];
    float m0 = u0 - u1 - u2;
    float m1 = u0 + u1 + u2;
    float m2 = u0 + u1 - u2;
    float m3 = u0 - u1 + u2;
    float st[6], o[6];
#pragma unroll
    for (int j = 0; j < 6; ++j) st[j] = state[6 * i + j];
    mecanum_elem(st, m0, m1, m2, m3, o);
#pragma unroll
    for (int j = 0; j < 6; ++j) out[6 * i + j] = o[j];
}

extern "C" void kernel_launch(void* const* d_in, const int* in_sizes, int n_in,
                              void* d_out, int out_size, void* d_ws, size_t ws_size,
                              hipStream_t stream) {
    // inputs: d_in[0] = t (1, unused), d_in[1] = state (BATCH*6), d_in[2] = control_duty (3)
    const float* state = (const float*)d_in[1];
    const float* cd    = (const float*)d_in[2];
    float* out         = (float*)d_out;

    int n = in_sizes[1] / 6;        // batch size
    int n_pairs = n / 2;

    if (n_pairs > 0) {
        int ntiles = (n_pairs + PAIRS_PER_BLOCK - 1) / PAIRS_PER_BLOCK;
        int grid = ntiles < GRID_BLOCKS ? ntiles : GRID_BLOCKS;
        mecanum_pipe_kernel<<<grid, 256, 0, stream>>>(
            (const float4*)state, cd, (float4*)out, n_pairs);
    }
    if (n & 1) {
        mecanum_tail_kernel<<<1, 64, 0, stream>>>(state, cd, out, 2 * n_pairs, n);
    }
}

// Round 4
// 174.973 us; speedup vs baseline: 1.0100x; 1.0100x over previous
//
#include <hip/hip_runtime.h>
#include <math.h>

// ---- compile-time physical constants (mirror the Python reference) ----
namespace k {
constexpr double dA     = 0.129907 + 0.095724;       // L_X + L_Y
constexpr double dR     = 4.0 * 0.0254;              // wheel radius
constexpr double dI     = 6.0;                       // inertia (== mass)
constexpr double dMOI   = 6.0 * (12.0 * 0.0254) * (12.0 * 0.0254) / 6.0;
constexpr float T_STALL   = (float)(5.4 / 100.0);
constexpr float INV_WFREE = (float)(1.0 / (1620.0 / 60.0 * 2.0 * 3.14159265358979323846));
constexpr float A         = (float)dA;
constexpr float INV_R     = (float)(1.0 / dR);
constexpr float INV_RI    = (float)(1.0 / (dR * dI));    // WT2LA rows 0,1 scale
constexpr float A_RMOI    = (float)(dA / (dR * dMOI));   // WT2LA row 2 scale
}

typedef float f32x4 __attribute__((ext_vector_type(4)));
typedef float f32x2 __attribute__((ext_vector_type(2)));

__device__ __forceinline__ float wheel_torque(float w, float m) {
    float p = m * w;
    // jnp.sign semantics: sign(0)=0 -> is_same_direction = 0.5
    float sgn = (float)(p > 0.0f) - (float)(p < 0.0f);
    float isd = 0.5f * (sgn + 1.0f);
    return k::T_STALL * (1.0f - fabsf(w) * isd * k::INV_WFREE) * m;
}

// ---------------------------------------------------------------------------
// R4: direct, LDS-free ablation kernel.
//
// Evidence: R0 (2-barrier LDS, 49% occ), R2 (barrier-free, ~100% occ), and
// R3 (persistent double-buffered pipeline) ALL measure 57-59 us with
// identical counters (VALUBusy 19%, HBM 31%, same FETCH/WRITE). Occupancy
// and cross-tile pipelining are proven non-levers. The shared invariant is
// the LDS round-trip chain (12 DS ops + lgkmcnt/vmcnt fences per pair) --
// so this round deletes it.
//
// Key realization: the reference never reads state[...,0:2] (positions).
// Each element needs only [theta, v0, v1, v2] = 16 B at byte 24*i+8
// (8-aligned), and writes [v0,v1,v2,a0] (16 B at 24*i) + [a1,a2] (8 B at
// 24*i+16), both 8-aligned. One thread = one element, zero cross-lane
// exchange, zero LDS, zero barriers. Per-wave accesses span 24 cache
// lines/instr (vs 16 coalesced) -> ~1.5x TA line requests, but total TA
// cost ~7 us/CU-worth, far below the 57 us floor being probed.
//
// Also: sincosf -> __sinf/__cosf (HW v_sin/v_cos; |theta|<~6, tolerance
// 7.8e-3 vs native error ~1e-6).
// ---------------------------------------------------------------------------
__global__ __launch_bounds__(256) void mecanum_direct_kernel(
    const float* __restrict__ state,
    const float* __restrict__ cd,
    float* __restrict__ out,
    int n) {
    int i = blockIdx.x * 256 + threadIdx.x;
    if (i >= n) return;

    // batch-uniform motor duty: CD2MD @ control_duty (scalar s_load path)
    float u0 = cd[0], u1 = cd[1], u2 = cd[2];
    float m0 = u0 - u1 - u2;
    float m1 = u0 + u1 + u2;
    float m2 = u0 + u1 - u2;
    float m3 = u0 - u1 + u2;

    // ---- load [theta, v0, v1, v2]: 16 B @ byte 24*i+8 (8-aligned) ----
    f32x4 tv;
    __builtin_memcpy(&tv, state + 6 * i + 2, 16);
    float theta = tv.x, v0 = tv.y, v1 = tv.z, v2 = tv.w;

    float s = __sinf(theta);
    float c = __cosf(theta);

    // a2l = rot(cos(-t), sin(-t)) -> [[c, s, 0], [-s, c, 0], [0,0,1]]
    float lv0 = c * v0 + s * v1;
    float lv1 = c * v1 - s * v0;

    // wheel_vel = LV2WV @ local_vel
    float al2 = k::A * v2;
    float w0 = (lv0 - lv1 - al2) * k::INV_R;
    float w1 = (lv0 + lv1 + al2) * k::INV_R;
    float w2 = (lv0 + lv1 - al2) * k::INV_R;
    float w3 = (lv0 - lv1 + al2) * k::INV_R;

    float t0 = wheel_torque(w0, m0);
    float t1 = wheel_torque(w1, m1);
    float t2 = wheel_torque(w2, m2);
    float t3 = wheel_torque(w3, m3);

    // local_accel = WT2LA @ torque
    float la0 = (t0 + t1 + t2 + t3) * k::INV_RI;
    float la1 = (-t0 + t1 + t2 - t3) * k::INV_RI;
    float la2 = (-t0 + t1 - t2 + t3) * k::A_RMOI;

    // l2a = rot(cos(t), sin(t)) -> [[c,-s,0],[s,c,0],[0,0,1]]
    float aa0 = c * la0 - s * la1;
    float aa1 = s * la0 + c * la1;

    // ---- store [v0,v1,v2,aa0] @ 24*i (16 B) + [aa1,la2] @ 24*i+16 (8 B) ----
    f32x4 o1; o1.x = v0; o1.y = v1; o1.z = v2; o1.w = aa0;
    __builtin_memcpy(out + 6 * i, &o1, 16);
    f32x2 o2; o2.x = aa1; o2.y = la2;
    __builtin_memcpy(out + 6 * i + 4, &o2, 8);
}

extern "C" void kernel_launch(void* const* d_in, const int* in_sizes, int n_in,
                              void* d_out, int out_size, void* d_ws, size_t ws_size,
                              hipStream_t stream) {
    // inputs: d_in[0] = t (1, unused), d_in[1] = state (BATCH*6), d_in[2] = control_duty (3)
    const float* state = (const float*)d_in[1];
    const float* cd    = (const float*)d_in[2];
    float* out         = (float*)d_out;

    int n = in_sizes[1] / 6;        // batch size

    if (n > 0) {
        int grid = (n + 255) / 256;
        mecanum_direct_kernel<<<grid, 256, 0, stream>>>(state, cd, out, n);
    }
}

// Round 5
// 174.611 us; speedup vs baseline: 1.0121x; 1.0021x over previous
//
#include <hip/hip_runtime.h>
#include <math.h>

// ---- compile-time physical constants (mirror the Python reference) ----
namespace k {
constexpr double dA     = 0.129907 + 0.095724;       // L_X + L_Y
constexpr double dR     = 4.0 * 0.0254;              // wheel radius
constexpr double dI     = 6.0;                       // inertia (== mass)
constexpr double dMOI   = 6.0 * (12.0 * 0.0254) * (12.0 * 0.0254) / 6.0;
constexpr float T_STALL   = (float)(5.4 / 100.0);
constexpr float INV_WFREE = (float)(1.0 / (1620.0 / 60.0 * 2.0 * 3.14159265358979323846));
constexpr float A         = (float)dA;
constexpr float INV_R     = (float)(1.0 / dR);
constexpr float INV_RI    = (float)(1.0 / (dR * dI));    // WT2LA rows 0,1 scale
constexpr float A_RMOI    = (float)(dA / (dR * dMOI));   // WT2LA row 2 scale
}

typedef float f32x4 __attribute__((ext_vector_type(4)));
typedef float f32x2 __attribute__((ext_vector_type(2)));

__device__ __forceinline__ float wheel_torque(float w, float m) {
    float p = m * w;
    // jnp.sign semantics: sign(0)=0 -> is_same_direction = 0.5
    float sgn = (float)(p > 0.0f) - (float)(p < 0.0f);
    float isd = 0.5f * (sgn + 1.0f);
    return k::T_STALL * (1.0f - fabsf(w) * isd * k::INV_WFREE) * m;
}

// Compute one element from its packed [theta, v0, v1, v2] vector; write via
// one 16 B + one 8 B store (output bytes [24i, 24i+24) fully covered).
__device__ __forceinline__ void mecanum_compute_store(
    f32x4 tv, float m0, float m1, float m2, float m3, float* __restrict__ outp) {
    float theta = tv.x, v0 = tv.y, v1 = tv.z, v2 = tv.w;

    float s = __sinf(theta);
    float c = __cosf(theta);

    // a2l = rot(cos(-t), sin(-t)) -> [[c, s, 0], [-s, c, 0], [0,0,1]]
    float lv0 = c * v0 + s * v1;
    float lv1 = c * v1 - s * v0;

    float al2 = k::A * v2;
    float w0 = (lv0 - lv1 - al2) * k::INV_R;
    float w1 = (lv0 + lv1 + al2) * k::INV_R;
    float w2 = (lv0 + lv1 - al2) * k::INV_R;
    float w3 = (lv0 - lv1 + al2) * k::INV_R;

    float t0 = wheel_torque(w0, m0);
    float t1 = wheel_torque(w1, m1);
    float t2 = wheel_torque(w2, m2);
    float t3 = wheel_torque(w3, m3);

    float la0 = (t0 + t1 + t2 + t3) * k::INV_RI;
    float la1 = (-t0 + t1 + t2 - t3) * k::INV_RI;
    float la2 = (-t0 + t1 - t2 + t3) * k::A_RMOI;

    // l2a = rot(cos(t), sin(t)) -> [[c,-s,0],[s,c,0],[0,0,1]]
    float aa0 = c * la0 - s * la1;
    float aa1 = s * la0 + c * la1;

    f32x4 o1; o1.x = v0; o1.y = v1; o1.z = v2; o1.w = aa0;
    __builtin_memcpy(outp, &o1, 16);
    f32x2 o2; o2.x = aa1; o2.y = la2;
    __builtin_memcpy(outp + 4, &o2, 8);
}

// ---------------------------------------------------------------------------
// R5: MLP-4 discriminating probe.
//
// History: R0 (LDS+barriers), R2 (barrier-free LDS, 2x occupancy), R3
// (persistent double-buffered pipeline), R4 (direct, no LDS, native trig)
// ALL land at 55.5-58 us. No counter shows a saturated pipe (VALU 19%,
// HBM 31%, LDS conflicts trivial). Remaining untested lever: per-thread
// memory-level parallelism WITHOUT fences (R3's prefetch sat between
// wave_barrier/memory-clobber pairs; R4 has MLP=1).
//
// This kernel: each thread owns 4 elements from 4 streams separated by
// T = ceil(n/4): {t, t+T, t+2T, t+3T}. All four independent 16 B loads are
// issued back-to-back (no fence, no LDS); compiler places one waitcnt
// before first use. Per-instruction lane pattern is identical to R4
// (24 B stride), so TA/L1 cost is unchanged -- only in-flight loads x4.
//
// Pre-committed read: if latency-underfeed was the floor -> kernel ~30-35us.
// If unchanged +-3% -> floor is environmental (DRAM saturated by harness
// fill L3-writeback drain during our window) -> declare roofline.
// ---------------------------------------------------------------------------
__global__ __launch_bounds__(256) void mecanum_ilp4_kernel(
    const float* __restrict__ state,
    const float* __restrict__ cd,
    float* __restrict__ out,
    int n, int T) {
    int t = blockIdx.x * 256 + threadIdx.x;
    if (t >= T) return;

    // batch-uniform motor duty: CD2MD @ control_duty
    float u0 = cd[0], u1 = cd[1], u2 = cd[2];
    float m0 = u0 - u1 - u2;
    float m1 = u0 + u1 + u2;
    float m2 = u0 + u1 - u2;
    float m3 = u0 - u1 + u2;

    int i0 = t;
    int i1 = t + T;
    int i2 = t + 2 * T;
    int i3 = t + 3 * T;

    // ---- issue all independent loads back-to-back (MLP = 4/thread) ----
    f32x4 tv0, tv1, tv2, tv3;
    bool p1 = i1 < n, p2 = i2 < n, p3 = i3 < n;   // i0 < T <= n always
    __builtin_memcpy(&tv0, state + 6 * i0 + 2, 16);
    if (p1) __builtin_memcpy(&tv1, state + 6 * i1 + 2, 16);
    if (p2) __builtin_memcpy(&tv2, state + 6 * i2 + 2, 16);
    if (p3) __builtin_memcpy(&tv3, state + 6 * i3 + 2, 16);

    // ---- compute + store each ----
    mecanum_compute_store(tv0, m0, m1, m2, m3, out + 6 * i0);
    if (p1) mecanum_compute_store(tv1, m0, m1, m2, m3, out + 6 * i1);
    if (p2) mecanum_compute_store(tv2, m0, m1, m2, m3, out + 6 * i2);
    if (p3) mecanum_compute_store(tv3, m0, m1, m2, m3, out + 6 * i3);
}

extern "C" void kernel_launch(void* const* d_in, const int* in_sizes, int n_in,
                              void* d_out, int out_size, void* d_ws, size_t ws_size,
                              hipStream_t stream) {
    // inputs: d_in[0] = t (1, unused), d_in[1] = state (BATCH*6), d_in[2] = control_duty (3)
    const float* state = (const float*)d_in[1];
    const float* cd    = (const float*)d_in[2];
    float* out         = (float*)d_out;

    int n = in_sizes[1] / 6;        // batch size
    if (n <= 0) return;

    int T = (n + 3) / 4;            // stream stride; threads cover [0, T)
    int grid = (T + 255) / 256;
    mecanum_ilp4_kernel<<<grid, 256, 0, stream>>>(state, cd, out, n, T);
}